// Round 11
// baseline (59.784 us; speedup 1.0000x reference)
//
#include <hip/hip_runtime.h>
#include <hip/hip_bf16.h>

// out[n,f] = weights[n] * ( x[n,:] . Wsum[f,:] + bsum[f] )
// Wsum = sum_e W[e], bsum = sum_e b[e]  (expert sum commutes with Linear).
// Wsum stored fragment-major ("Bfrag", R6-proven) -> B-loads are dense lane-
// consecutive streams. R10: unwedge the VGPR corner -- 4-wave blocks (BM=64 x
// BF=256, grid 1024) leave only 8 waves/CU, so each wave gets ~256 VGPR budget:
// depth-2 B prefetch (3 sets) + 1-slice-ahead A ds_reads (2 sets) with no
// TLP loss (R5/R7/R9's pipelining attempts all silently halved residency).

#define N_TOK 32768
#define DIM   512
#define NEXP  8
#define BM    64            // tokens per block
#define BFB   256           // features per block (4 waves x 64)

typedef __attribute__((ext_vector_type(8))) short  bf16x8;
typedef __attribute__((ext_vector_type(4))) float  f32x4;

__device__ __forceinline__ unsigned int pk2bf(float a, float b) {
    unsigned ua = __float_as_uint(a), ub = __float_as_uint(b);
    ua = (ua + 0x7FFFu + ((ua >> 16) & 1u)) >> 16;   // RNE to bf16
    ub = (ub + 0x7FFFu + ((ub >> 16) & 1u)) >> 16;
    return ua | (ub << 16);
}

// ---------------- prep: Bfrag (bf16, fragment-major) + bsum (f32) ----------------
// R10: 512 blocks x 64 threads (was 128x256 -- half the CUs sat idle).
__global__ __launch_bounds__(64) void moe_prep(const float* __restrict__ W,
                                               const float* __restrict__ b,
                                               unsigned short* __restrict__ Bfrag,
                                               float* __restrict__ bsum) {
    const int g = blockIdx.x * 64 + threadIdx.x;     // 0..32767
    const int f = g >> 6;
    const int q = g & 63;
    const float* src = W + (size_t)f * DIM + q * 8;
    float s0 = 0, s1 = 0, s2 = 0, s3 = 0, s4 = 0, s5 = 0, s6 = 0, s7 = 0;
#pragma unroll
    for (int e = 0; e < NEXP; ++e) {
        float4 u0 = *(const float4*)(src + (size_t)e * DIM * DIM);
        float4 u1 = *(const float4*)(src + (size_t)e * DIM * DIM + 4);
        s0 += u0.x; s1 += u0.y; s2 += u0.z; s3 += u0.w;
        s4 += u1.x; s5 += u1.y; s6 += u1.z; s7 += u1.w;
    }
    uint4 v;
    v.x = pk2bf(s0, s1); v.y = pk2bf(s2, s3);
    v.z = pk2bf(s4, s5); v.w = pk2bf(s6, s7);

    const int F  = f >> 6, j = (f >> 4) & 3, lr = f & 15;
    const int sl = q >> 2, lg = q & 3;
    const int idx16 = ((F * 4 + j) * 16 + sl) * 64 + (lg * 16 + lr);
    *(uint4*)(Bfrag + (size_t)idx16 * 8) = v;

    if (g < DIM / 4) {
        float4 bs = make_float4(0.f, 0.f, 0.f, 0.f);
#pragma unroll
        for (int e = 0; e < NEXP; ++e) {
            float4 u = *(const float4*)(b + e * DIM + g * 4);
            bs.x += u.x; bs.y += u.y; bs.z += u.z; bs.w += u.w;
        }
        *(float4*)(bsum + g * 4) = bs;
    }
}

// ---------------- main GEMM ----------------
// Block = 64 tokens x 256 features; 4 waves, wave w owns features
// [h*256 + w*64, +64) where h = blockIdx&1. Grid 1024.
// A (x, f32->bf16) staged ONCE into 64KB LDS (XOR-swizzled), 1 barrier.
// K-loop: depth-2 B prefetch (bA/bB/bC), 1-ahead A ds_reads (afE/afO), 16 MFMA/slice.
__global__ __launch_bounds__(256, 2) void moe_gemm(const float* __restrict__ x,
                                                   const float* __restrict__ wts,
                                                   const unsigned short* __restrict__ Bf,
                                                   const float* __restrict__ bsum,
                                                   float* __restrict__ out) {
    __shared__ __align__(16) unsigned char ldsA[BM * DIM * 2];   // 64 KB

    const int tid  = threadIdx.x;
    const int lane = tid & 63;
    const int w    = tid >> 6;       // wave 0..3
    const int lr   = lane & 15;
    const int lg   = lane >> 4;
    const int mt   = blockIdx.x >> 1;        // token tile 0..511
    const int h    = blockIdx.x & 1;         // feature half
    const int m0   = mt * BM;
    const int f0   = h * BFB + w * 64;

    // ---- stage A once: thread -> row tid>>2 (0..63), granule slot s0 = tid&3.
    //      Granules g = s0 + u*4 (u=0..15), each 8 f32 -> 16B bf16, XOR-swizzled.
    {
        const int row = tid >> 2;
        const int s0  = tid & 3;
        const float* src = x + (size_t)(m0 + row) * DIM;
        unsigned char* dst = ldsA + row * 1024;
#pragma unroll
        for (int u = 0; u < 16; ++u) {
            const int g  = s0 + u * 4;
            float4 u0 = *(const float4*)(src + g * 8);
            float4 u1 = *(const float4*)(src + g * 8 + 4);
            const int sg = (g & ~7) | ((g ^ row) & 7);
            uint4 v;
            v.x = pk2bf(u0.x, u0.y); v.y = pk2bf(u0.z, u0.w);
            v.z = pk2bf(u1.x, u1.y); v.w = pk2bf(u1.z, u1.w);
            *(uint4*)(dst + sg * 16) = v;
        }
    }
    __syncthreads();   // the ONLY barrier

    // ---- dense B stream base: fragment slice (h*4 + w), this lane's 16B slot
    const bf16x8* bfr = (const bf16x8*)Bf + (size_t)(h * 4 + w) * 4096 + lane;

    f32x4 acc[4][4] = {};   // acc[j][i]: j = feature frag, i = token frag
    bf16x8 bA[4], bB[4], bC[4], afE[4], afO[4];

    auto loadB = [&](int s, bf16x8 (&bb)[4]) {
#pragma unroll
        for (int j = 0; j < 4; ++j)
            bb[j] = bfr[j * 1024 + s * 64];
    };
    auto sliceA = [&](int s, bf16x8 (&aa)[4]) {
#pragma unroll
        for (int i = 0; i < 4; ++i) {
            const int row = i * 16 + lr;
            const int gsl = s * 4 + lg;
            const int sw  = (gsl & ~7) | ((gsl ^ row) & 7);
            aa[i] = *(const bf16x8*)(ldsA + row * 1024 + sw * 16);
        }
    };
    auto mf = [&](bf16x8 (&bb)[4], bf16x8 (&aa)[4]) {
#pragma unroll
        for (int j = 0; j < 4; ++j)
#pragma unroll
            for (int i = 0; i < 4; ++i)
                acc[j][i] = __builtin_amdgcn_mfma_f32_16x16x32_bf16(bb[j], aa[i], acc[j][i], 0, 0, 0);
    };

    // ---- K-loop: slice s uses B set s%3 (loaded at s-2) and af set s&1 (loaded at s-1)
    loadB(0, bA); loadB(1, bB);
    sliceA(0, afE);
#define STEP(s, BU, BL, AU, AL)                     \
    { if ((s) + 2 < 16) loadB((s) + 2, BL);         \
      if ((s) + 1 < 16) sliceA((s) + 1, AL);        \
      mf(BU, AU); }
    STEP(0,  bA, bC, afE, afO)
    STEP(1,  bB, bA, afO, afE)
    STEP(2,  bC, bB, afE, afO)
    STEP(3,  bA, bC, afO, afE)
    STEP(4,  bB, bA, afE, afO)
    STEP(5,  bC, bB, afO, afE)
    STEP(6,  bA, bC, afE, afO)
    STEP(7,  bB, bA, afO, afE)
    STEP(8,  bC, bB, afE, afO)
    STEP(9,  bA, bC, afO, afE)
    STEP(10, bB, bA, afE, afO)
    STEP(11, bC, bB, afO, afE)
    STEP(12, bA, bC, afE, afO)
    STEP(13, bB, bA, afO, afE)
    STEP(14, bC, bB, afE, afO)
    STEP(15, bA, bC, afO, afE)
#undef STEP

    // ---- epilogue: direct stores. token = m0 + i*16 + lr; feats = f0 + j*16 + lg*4
    f32x4 bs4[4];
#pragma unroll
    for (int j = 0; j < 4; ++j)
        bs4[j] = *(const f32x4*)(bsum + f0 + j * 16 + lg * 4);

#pragma unroll
    for (int i = 0; i < 4; ++i) {
        const int row = m0 + i * 16 + lr;
        const float wt = wts[row];
#pragma unroll
        for (int j = 0; j < 4; ++j) {
            f32x4 v;
            v[0] = wt * (acc[j][i][0] + bs4[j][0]);
            v[1] = wt * (acc[j][i][1] + bs4[j][1]);
            v[2] = wt * (acc[j][i][2] + bs4[j][2]);
            v[3] = wt * (acc[j][i][3] + bs4[j][3]);
            *(f32x4*)(out + (size_t)row * DIM + f0 + j * 16 + lg * 4) = v;
        }
    }
}

extern "C" void kernel_launch(void* const* d_in, const int* in_sizes, int n_in,
                              void* d_out, int out_size, void* d_ws, size_t ws_size,
                              hipStream_t stream) {
    const float* x   = (const float*)d_in[0];   // [N, D]
    const float* wts = (const float*)d_in[1];   // [N, 1]
    const float* W   = (const float*)d_in[2];   // [E, D, D]
    const float* b   = (const float*)d_in[3];   // [E, D]
    float* out       = (float*)d_out;           // [N, D]

    unsigned short* Bfrag = (unsigned short*)d_ws;                    // 512 KB bf16
    float*          bsum  = (float*)((char*)d_ws + DIM * DIM * 2);    // 2 KB f32

    moe_prep<<<dim3((DIM * DIM / 8) / 64), dim3(64), 0, stream>>>(W, b, Bfrag, bsum);

    moe_gemm<<<dim3((N_TOK / BM) * (DIM / BFB)), dim3(256), 0, stream>>>(x, wts, Bfrag, bsum, out);
}

// Round 12
// 43.574 us; speedup vs baseline: 1.3720x; 1.3720x over previous
//
#include <hip/hip_runtime.h>
#include <hip/hip_bf16.h>

// out[n,f] = weights[n] * ( x[n,:] . Wsum[f,:] + bsum[f] )
// Wsum = sum_e W[e], bsum = sum_e b[e]  (expert sum commutes with Linear).
// Wsum stored fragment-major ("Bfrag", R6-proven) -> B-loads are dense lane-
// consecutive streams. R11: producer-consumer wave specialization -- 12-wave
// blocks (8 compute + 4 stagers), 2 tiles/block, LDS double-buffer. Stagers
// stage tile t+1 WHILE compute waves run tile t's K-loop; tile-0 stores drain
// under tile-1 compute. Attacks the chip-wide phase serialization that R5/R7/
// R9/R10's instruction-level attempts couldn't (compiler sinking, vmcnt drains).

#define N_TOK 32768
#define DIM   512
#define NEXP  8
#define BM    64            // tokens per tile
#define TILES 2             // tiles per block

typedef __attribute__((ext_vector_type(8))) short  bf16x8;
typedef __attribute__((ext_vector_type(4))) float  f32x4;

__device__ __forceinline__ unsigned int pk2bf(float a, float b) {
    unsigned ua = __float_as_uint(a), ub = __float_as_uint(b);
    ua = (ua + 0x7FFFu + ((ua >> 16) & 1u)) >> 16;   // RNE to bf16
    ub = (ub + 0x7FFFu + ((ub >> 16) & 1u)) >> 16;
    return ua | (ub << 16);
}

// ---------------- prep: Bfrag (bf16, fragment-major) + bsum (f32) ---- (proven) ----
__global__ __launch_bounds__(64) void moe_prep(const float* __restrict__ W,
                                               const float* __restrict__ b,
                                               unsigned short* __restrict__ Bfrag,
                                               float* __restrict__ bsum) {
    const int g = blockIdx.x * 64 + threadIdx.x;     // 0..32767
    const int f = g >> 6;
    const int q = g & 63;
    const float* src = W + (size_t)f * DIM + q * 8;
    float s0 = 0, s1 = 0, s2 = 0, s3 = 0, s4 = 0, s5 = 0, s6 = 0, s7 = 0;
#pragma unroll
    for (int e = 0; e < NEXP; ++e) {
        float4 u0 = *(const float4*)(src + (size_t)e * DIM * DIM);
        float4 u1 = *(const float4*)(src + (size_t)e * DIM * DIM + 4);
        s0 += u0.x; s1 += u0.y; s2 += u0.z; s3 += u0.w;
        s4 += u1.x; s5 += u1.y; s6 += u1.z; s7 += u1.w;
    }
    uint4 v;
    v.x = pk2bf(s0, s1); v.y = pk2bf(s2, s3);
    v.z = pk2bf(s4, s5); v.w = pk2bf(s6, s7);

    const int F  = f >> 6, j = (f >> 4) & 3, lr = f & 15;
    const int sl = q >> 2, lg = q & 3;
    const int idx16 = ((F * 4 + j) * 16 + sl) * 64 + (lg * 16 + lr);
    *(uint4*)(Bfrag + (size_t)idx16 * 8) = v;

    if (g < DIM / 4) {
        float4 bs = make_float4(0.f, 0.f, 0.f, 0.f);
#pragma unroll
        for (int e = 0; e < NEXP; ++e) {
            float4 u = *(const float4*)(b + e * DIM + g * 4);
            bs.x += u.x; bs.y += u.y; bs.z += u.z; bs.w += u.w;
        }
        *(float4*)(bsum + g * 4) = bs;
    }
}

// ---------------- main GEMM: producer-consumer, 2 tiles, LDS dbuf ----------------
// Grid 256 (1 block/CU via 128KB LDS). Block = 12 waves: w0-7 compute (wave w owns
// features [w*64,(w+1)*64) of 64 tokens), w8-11 stage. Barriers in UNIFORM control
// flow (role predication inside shared code); wave-uniform role branches only.
__global__ __launch_bounds__(768) void moe_gemm(const float* __restrict__ x,
                                                const float* __restrict__ wts,
                                                const unsigned short* __restrict__ Bf,
                                                const float* __restrict__ bsum,
                                                float* __restrict__ out) {
    __shared__ __align__(16) unsigned char ldsA[2][BM * DIM * 2];   // 2 x 64 KB

    const int tid  = threadIdx.x;
    const int lane = tid & 63;
    const int w    = tid >> 6;       // 0..11
    const bool stager = (w >= 8);
    const int lr   = lane & 15;
    const int lg   = lane >> 4;
    const int blk  = blockIdx.x;
    const int f0   = w * 64;         // compute waves only

    // ---- stager geometry: thread st=tid-512 (0..255) -> row st>>2, slot st&3
    const int st   = tid - 512;
    const int arow = (st >> 2) & 63;
    const int as0  = st & 3;

    auto stage = [&](int tile, int buf) {
        const float* src = x + (size_t)((blk * TILES + tile) * BM + arow) * DIM;
        unsigned char* dst = ldsA[buf] + arow * 1024;
#pragma unroll
        for (int u = 0; u < 16; ++u) {
            const int g  = as0 + u * 4;
            float4 u0 = *(const float4*)(src + g * 8);
            float4 u1 = *(const float4*)(src + g * 8 + 4);
            const int sg = (g & ~7) | ((g ^ arow) & 7);   // XOR swizzle (proven pair)
            uint4 v;
            v.x = pk2bf(u0.x, u0.y); v.y = pk2bf(u0.z, u0.w);
            v.z = pk2bf(u1.x, u1.y); v.w = pk2bf(u1.z, u1.w);
            *(uint4*)(dst + sg * 16) = v;
        }
    };

    // ---- compute lambdas (R6-proven, verbatim modulo buffer param)
    const bf16x8* bfr = (const bf16x8*)Bf + (size_t)w * 4096 + lane;   // + j*1024 + s*64

    f32x4 acc[4][4];
    bf16x8 bE[4], bO[4], af[4];

    auto loadB = [&](int s, bf16x8 (&bb)[4]) {
#pragma unroll
        for (int j = 0; j < 4; ++j)
            bb[j] = bfr[j * 1024 + s * 64];
    };
    auto sliceA = [&](int buf, int s) {
#pragma unroll
        for (int i = 0; i < 4; ++i) {
            const int row = i * 16 + lr;
            const int gsl = s * 4 + lg;
            const int sw  = (gsl & ~7) | ((gsl ^ row) & 7);
            af[i] = *(const bf16x8*)(ldsA[buf] + row * 1024 + sw * 16);
        }
    };
    auto mf = [&](bf16x8 (&bb)[4]) {
#pragma unroll
        for (int j = 0; j < 4; ++j)
#pragma unroll
            for (int i = 0; i < 4; ++i)
                acc[j][i] = __builtin_amdgcn_mfma_f32_16x16x32_bf16(bb[j], af[i], acc[j][i], 0, 0, 0);
    };
    auto kloop = [&](int buf) {
#pragma unroll
        for (int j = 0; j < 4; ++j)
#pragma unroll
            for (int i = 0; i < 4; ++i)
                acc[j][i] = f32x4{0.f, 0.f, 0.f, 0.f};
        loadB(0, bE);
#pragma unroll
        for (int it = 0; it < 8; ++it) {
            loadB(2 * it + 1, bO);                      // prefetch odd slice
            sliceA(buf, 2 * it);
            mf(bE);
            if (it < 7) loadB(2 * it + 2, bE);          // prefetch even slice
            sliceA(buf, 2 * it + 1);
            mf(bO);
        }
    };
    auto epilogue = [&](int tile) {
        const int m0 = (blk * TILES + tile) * BM;
        f32x4 bs4[4];
#pragma unroll
        for (int j = 0; j < 4; ++j)
            bs4[j] = *(const f32x4*)(bsum + f0 + j * 16 + lg * 4);
#pragma unroll
        for (int i = 0; i < 4; ++i) {
            const int row = m0 + i * 16 + lr;
            const float wt = wts[row];
#pragma unroll
            for (int j = 0; j < 4; ++j) {
                f32x4 v;
                v[0] = wt * (acc[j][i][0] + bs4[j][0]);
                v[1] = wt * (acc[j][i][1] + bs4[j][1]);
                v[2] = wt * (acc[j][i][2] + bs4[j][2]);
                v[3] = wt * (acc[j][i][3] + bs4[j][3]);
                *(f32x4*)(out + (size_t)row * DIM + f0 + j * 16 + lg * 4) = v;
            }
        }
    };

    // ================= schedule =================
    if (stager) stage(0, 0);          // stagers fill buf0; compute waves fall through
    __syncthreads();                  // bar1: buf0 ready

    if (stager) stage(1, 1);          // stage tile1 WHILE compute runs tile0
    else        kloop(0);             // tile0 compute (A from buf0, B from L2)
    __syncthreads();                  // bar2: buf1 ready, buf0 free

    if (!stager) {
        epilogue(0);                  // tile0 stores issue; drain under tile1 kloop
        kloop(1);                     // tile1 compute
        epilogue(1);                  // tail drain
    }
}

extern "C" void kernel_launch(void* const* d_in, const int* in_sizes, int n_in,
                              void* d_out, int out_size, void* d_ws, size_t ws_size,
                              hipStream_t stream) {
    const float* x   = (const float*)d_in[0];   // [N, D]
    const float* wts = (const float*)d_in[1];   // [N, 1]
    const float* W   = (const float*)d_in[2];   // [E, D, D]
    const float* b   = (const float*)d_in[3];   // [E, D]
    float* out       = (float*)d_out;           // [N, D]

    unsigned short* Bfrag = (unsigned short*)d_ws;                    // 512 KB bf16
    float*          bsum  = (float*)((char*)d_ws + DIM * DIM * 2);    // 2 KB f32

    moe_prep<<<dim3((DIM * DIM / 8) / 64), dim3(64), 0, stream>>>(W, b, Bfrag, bsum);

    moe_gemm<<<dim3(N_TOK / (BM * TILES)), dim3(768), 0, stream>>>(x, wts, Bfrag, bsum, out);
}